// Round 6
// baseline (117.956 us; speedup 1.0000x reference)
//
#include <hip/hip_runtime.h>

#define NROWS 8192
#define HALF_N 4096
#define DIM 512
#define INV_T 10.0f
#define NRB 64              // number of 128-row blocks
#define NBLOCKS 2080        // 64*65/2 upper-triangle block pairs

typedef __attribute__((ext_vector_type(4))) float f32x4;
typedef __attribute__((ext_vector_type(2))) long long2v;

// async 16B global -> LDS (DMA). LDS dest is wave-uniform base + lane*16.
__device__ __forceinline__ void async16(const void* g, void* l) {
  __builtin_amdgcn_global_load_lds(
      (const __attribute__((address_space(1))) unsigned int*)g,
      (__attribute__((address_space(3))) unsigned int*)l, 16, 0, 0);
}

// Kernel 1: L2-normalize rows of [f1;f2] -> fp8 e4m3 into Fb ONLY
// (A-fragments now come from LDS staged out of Fb too — Fa copy removed).
// Fb: row-major, k-permuted within each 64B group (unit u -> pos
// 2*(u&3)+(u>>2)) — R4-proven geometry for the LDS swizzle + b128 reads.
__global__ __launch_bounds__(256) void norm_cast_k(
    const float* __restrict__ f1, const float* __restrict__ f2,
    unsigned char* __restrict__ Fb, float* __restrict__ rowsum,
    float* __restrict__ out) {
  int wave = threadIdx.x >> 6;
  int lane = threadIdx.x & 63;
  int row = blockIdx.x * 4 + wave;
  const float* src = (row < HALF_N) ? (f1 + (size_t)row * DIM)
                                    : (f2 + (size_t)(row - HALF_N) * DIM);
  const float4* p = reinterpret_cast<const float4*>(src + lane * 8);
  float4 v0 = p[0];
  float4 v1 = p[1];
  float ss = v0.x*v0.x + v0.y*v0.y + v0.z*v0.z + v0.w*v0.w
           + v1.x*v1.x + v1.y*v1.y + v1.z*v1.z + v1.w*v1.w;
  #pragma unroll
  for (int off = 1; off < 64; off <<= 1) ss += __shfl_xor(ss, off);
  float scale = 1.0f / fmaxf(sqrtf(ss), 1e-12f);
  int lo = __builtin_amdgcn_cvt_pk_fp8_f32(v0.x * scale, v0.y * scale, 0, false);
  lo = __builtin_amdgcn_cvt_pk_fp8_f32(v0.z * scale, v0.w * scale, lo, true);
  int hi = __builtin_amdgcn_cvt_pk_fp8_f32(v1.x * scale, v1.y * scale, 0, false);
  hi = __builtin_amdgcn_cvt_pk_fp8_f32(v1.z * scale, v1.w * scale, hi, true);
  int2 val = make_int2(lo, hi);
  int u = lane & 7;                     // k-unit within 64B group
  int g = lane >> 3;                    // k-group (0..7)
  int pos = 2 * (u & 3) + (u >> 2);
  *reinterpret_cast<int2*>(Fb + (size_t)row * DIM + g * 64 + pos * 8) = val;
  if (lane == 0) rowsum[row] = 0.0f;
  if (blockIdx.x == 0 && threadIdx.x == 0) out[0] = 0.0f;
}

// Kernel 2: symmetric upper-triangle sim GEMM (fp8 e4m3 16x16x32, non-scaled;
// MX-scaled builtin spills v8i32 via scratch on this ROCm — R1-R3. No retry.)
//
// R6 structure (T4 counted-vmcnt, from the R4 base): 128x128 tiles, 4 waves.
// BOTH A and B staged from Fb into LDS by global_load_lds (A-fragment lane
// mapping lane<->row, quad<->k-chunk is IDENTICAL to B's, so the same DMA
// geometry+swizzle serves both). The K-loop then has NO other VMEM ops, so
// per-wave vmcnt counting is exact: 4-deep rolling slots per operand,
// prologue stages rounds 0-3, round kc waits vmcnt(12,12,12,12,12,8,4,0) —
// 3 rounds of DMAs always in flight, NEVER drained to 0 mid-loop (the
// __syncthreads vmcnt(0) drain was the m97-ceiling stall R4 sat at).
// Raw s_barrier (__syncthreads would re-introduce the drain) + sched_barrier
// fences; s_setprio(1) around the MFMA cluster (T5).
// LDS: A slots 4x8KB @0, B slots 4x8KB @32768 = 64 KB -> 2 blocks/CU.
// redrow/redcol alias slot A0 after the loop (dead by then; vmcnt(0) at
// round 7 guarantees no DMA in flight).
__global__ __launch_bounds__(256, 2) void sym_gemm_k(
    const unsigned char* __restrict__ Fb,
    float* __restrict__ rowsum, float* __restrict__ pairsim) {
  // XCD-contiguous remap: each XCD (bx%8) gets a contiguous 260-block range
  int bx = blockIdx.x;
  int gbx = (bx & 7) * (NBLOCKS / 8) + (bx >> 3);
  int rb = 0, rem = gbx;
  while (rem >= NRB - rb) { rem -= NRB - rb; ++rb; }
  const int cb = rb + rem;
  const int row0 = rb * 128, col0 = cb * 128;

  const int tid = threadIdx.x;
  const int wave = tid >> 6;
  const int lane = tid & 63;
  const int quad = lane >> 4;
  const int colid = lane & 15;
  const int wr0 = (wave >> 1) * 64;   // wave's row offset within tile
  const int wc0 = (wave & 1) * 64;    // wave's col offset within tile

  __shared__ __align__(16) unsigned char smem[65536];

  // Staging geometry (R4-proven): inst i covers rows [i*16,i*16+16);
  // lane -> r = i*16 + (lane>>2), phys 16B chunk = lane&3,
  // logical chunk = (lane&3) ^ ((r>>1)&3) = (lane&3) ^ (((lane>>2)>>1)&3).
  // Wave w owns insts {w, w+4} for A and the same for B.
  const int rloc = lane >> 2;
  const int lch = (lane & 3) ^ ((rloc >> 1) & 3);
  const unsigned char* srcA0 = Fb + (size_t)(row0 + wave * 16 + rloc) * DIM + lch * 16;
  const unsigned char* srcA1 = Fb + (size_t)(row0 + (wave + 4) * 16 + rloc) * DIM + lch * 16;
  const unsigned char* srcB0 = Fb + (size_t)(col0 + wave * 16 + rloc) * DIM + lch * 16;
  const unsigned char* srcB1 = Fb + (size_t)(col0 + (wave + 4) * 16 + rloc) * DIM + lch * 16;
  const int d0 = wave * 1024, d1 = (wave + 4) * 1024;

  // Fragment LDS byte offsets within a slot: row r, logical chunk quad ->
  // phys = quad ^ ((r>>1)&3); byte = r*64 + phys*16.
  int aoff[4], boff[4];
  #pragma unroll
  for (int t = 0; t < 4; ++t) {
    int ra = wr0 + t * 16 + colid;
    aoff[t] = ra * 64 + ((quad ^ ((ra >> 1) & 3)) << 4);
    int rc = wc0 + t * 16 + colid;
    boff[t] = rc * 64 + ((quad ^ ((rc >> 1) & 3)) << 4);
  }

  f32x4 acc[4][4];
  #pragma unroll
  for (int t = 0; t < 4; ++t)
    #pragma unroll
    for (int u = 0; u < 4; ++u) acc[t][u] = (f32x4){0.f, 0.f, 0.f, 0.f};

#define STAGE_ROUND(KC) { \
    unsigned char* As_ = smem + ((KC) & 3) * 8192; \
    unsigned char* Bs_ = smem + 32768 + ((KC) & 3) * 8192; \
    async16(srcA0 + (KC) * 64, As_ + d0); \
    async16(srcA1 + (KC) * 64, As_ + d1); \
    async16(srcB0 + (KC) * 64, Bs_ + d0); \
    async16(srcB1 + (KC) * 64, Bs_ + d1); \
    __builtin_amdgcn_sched_barrier(0); }

#define COMPUTE_ROUND(KC, VN) { \
    asm volatile("s_waitcnt vmcnt(" VN ")" ::: "memory"); \
    __builtin_amdgcn_s_barrier(); \
    __builtin_amdgcn_sched_barrier(0); \
    const unsigned char* Ab_ = smem + ((KC) & 3) * 8192; \
    const unsigned char* Bb_ = smem + 32768 + ((KC) & 3) * 8192; \
    long2v af[4], bf[4]; \
    _Pragma("unroll") \
    for (int t = 0; t < 4; ++t) \
      af[t] = *reinterpret_cast<const long2v*>(Ab_ + aoff[t]); \
    _Pragma("unroll") \
    for (int u = 0; u < 4; ++u) \
      bf[u] = *reinterpret_cast<const long2v*>(Bb_ + boff[u]); \
    __builtin_amdgcn_s_setprio(1); \
    _Pragma("unroll") \
    for (int s = 0; s < 2; ++s) \
      _Pragma("unroll") \
      for (int t = 0; t < 4; ++t) \
        _Pragma("unroll") \
        for (int u = 0; u < 4; ++u) \
          acc[t][u] = __builtin_amdgcn_mfma_f32_16x16x32_fp8_fp8( \
              af[t][s], bf[u][s], acc[t][u], 0, 0, 0); \
    __builtin_amdgcn_s_setprio(0); }

  // Prologue: rounds 0-3 issued back-to-back (16 DMAs/wave, kc-major order).
  STAGE_ROUND(0) STAGE_ROUND(1) STAGE_ROUND(2) STAGE_ROUND(3)

  // vmcnt math (per wave, 4 DMAs/round, in-order retirement): at round kc,
  // issued = 16 + 4*min(kc,4); required retired = 4*(kc+1);
  // N = {12,12,12,12,12,8,4,0}. The barrier after each wave's own vmcnt
  // makes round-kc data globally visible. Barrier before STAGE_ROUND(kc+4)
  // fences WAR on the slot being overwritten (all waves' reads done).
  COMPUTE_ROUND(0, "12")
  __builtin_amdgcn_s_barrier(); STAGE_ROUND(4)
  COMPUTE_ROUND(1, "12")
  __builtin_amdgcn_s_barrier(); STAGE_ROUND(5)
  COMPUTE_ROUND(2, "12")
  __builtin_amdgcn_s_barrier(); STAGE_ROUND(6)
  COMPUTE_ROUND(3, "12")
  __builtin_amdgcn_s_barrier(); STAGE_ROUND(7)
  COMPUTE_ROUND(4, "12")
  COMPUTE_ROUND(5, "8")
  COMPUTE_ROUND(6, "4")
  COMPUTE_ROUND(7, "0")

#undef STAGE_ROUND
#undef COMPUTE_ROUND

  // Epilogue. red arrays alias LDS slot A0 (dead: last read round 4, last
  // DMA retired by round 7's vmcnt(0); all waves past round-7 barrier).
  __syncthreads();
  float* redrow = reinterpret_cast<float*>(smem);
  float* redcol = reinterpret_cast<float*>(smem) + 128;
  if (tid < 128) redrow[tid] = 0.0f;
  else           redcol[tid - 128] = 0.0f;
  __syncthreads();

  // C/D layout: col = lane&15, row = quad*4 + reg (m89-verified).
  float re[4][4];
  float ce[4];
  #pragma unroll
  for (int t = 0; t < 4; ++t)
    #pragma unroll
    for (int r = 0; r < 4; ++r) re[t][r] = 0.0f;
  #pragma unroll
  for (int u = 0; u < 4; ++u) ce[u] = 0.0f;

  #pragma unroll
  for (int t = 0; t < 4; ++t) {
    #pragma unroll
    for (int u = 0; u < 4; ++u) {
      f32x4 a = acc[t][u];
      const int gc = col0 + wc0 + u * 16 + colid;
      #pragma unroll
      for (int r = 0; r < 4; ++r) {
        int grow = row0 + wr0 + t * 16 + quad * 4 + r;
        float sim = a[r] * INV_T;
        float e = (gc > grow) ? __expf(sim) : 0.0f;  // strict upper triangle
        re[t][r] += e;
        ce[u] += e;
        if (gc == grow + HALF_N && grow < HALF_N) {
          pairsim[grow] = sim;         // unique writer per pair
          pairsim[gc] = sim;
        }
      }
    }
  }

  // Row sums: reduce across the 16 col-lanes, LDS-accumulate.
  #pragma unroll
  for (int t = 0; t < 4; ++t)
    #pragma unroll
    for (int r = 0; r < 4; ++r) {
      float v = re[t][r];
      v += __shfl_xor(v, 1); v += __shfl_xor(v, 2);
      v += __shfl_xor(v, 4); v += __shfl_xor(v, 8);
      if (colid == 0) atomicAdd(&redrow[wr0 + t * 16 + quad * 4 + r], v);
    }
  // Col sums: reduce across the 4 quads (this wave's 64 rows).
  #pragma unroll
  for (int u = 0; u < 4; ++u) {
    float v = ce[u];
    v += __shfl_xor(v, 16); v += __shfl_xor(v, 32);
    if (lane < 16) atomicAdd(&redcol[wc0 + u * 16 + colid], v);
  }
  __syncthreads();
  if (tid < 128) atomicAdd(&rowsum[row0 + tid], redrow[tid]);
  else           atomicAdd(&rowsum[col0 + tid - 128], redcol[tid - 128]);
}

// Kernel 3: loss partials. 32 blocks x 256 threads, one row each;
// per-wave reduce then one atomicAdd per wave into out (zeroed in kernel 1).
__global__ __launch_bounds__(256) void finalize_k(
    const float* __restrict__ rowsum, const float* __restrict__ pairsim,
    float* __restrict__ out) {
  int i = blockIdx.x * 256 + threadIdx.x;
  float local = logf(rowsum[i]) - pairsim[i];
  #pragma unroll
  for (int off = 1; off < 64; off <<= 1) local += __shfl_xor(local, off);
  if ((threadIdx.x & 63) == 0)
    atomicAdd(out, local * (1.0f / (float)NROWS));
}

extern "C" void kernel_launch(void* const* d_in, const int* in_sizes, int n_in,
                              void* d_out, int out_size, void* d_ws, size_t ws_size,
                              hipStream_t stream) {
  const float* f1 = (const float*)d_in[0];
  const float* f2 = (const float*)d_in[1];
  unsigned char* Fb = (unsigned char*)d_ws;                     // 4 MB fp8
  float* rowsum = (float*)(Fb + (size_t)NROWS * DIM);
  float* pairsim = rowsum + NROWS;
  float* out = (float*)d_out;

  norm_cast_k<<<NROWS / 4, 256, 0, stream>>>(f1, f2, Fb, rowsum, out);
  sym_gemm_k<<<NBLOCKS, 256, 0, stream>>>(Fb, rowsum, pairsim);
  finalize_k<<<NROWS / 256, 256, 0, stream>>>(rowsum, pairsim, out);
}

// Round 7
// 107.164 us; speedup vs baseline: 1.1007x; 1.1007x over previous
//
#include <hip/hip_runtime.h>

#define NROWS 8192
#define HALF_N 4096
#define DIM 512
#define INV_T 10.0f
#define NRB 64              // number of 128-row blocks
#define NBLOCKS 2080        // 64*65/2 upper-triangle block pairs

typedef __attribute__((ext_vector_type(4))) float f32x4;
typedef __attribute__((ext_vector_type(2))) long long2v;

// Kernel 1: L2-normalize rows of [f1;f2] -> fp8 e4m3 into Fa ONLY.
// Fa: fragment-major — panel p = row>>4 is 8 KB laid out as
// [chunk c=0..31][row&15][16B], where chunk c holds k-units {c&3, (c&3)+4}
// of k-group c>>2. Both A and B fragment loads in the GEMM read this layout
// as coalesced global b128 (quarter-wave = 256 B contiguous): the MFMA
// B-operand lane mapping (col=colid, k-chunk=quad) mirrors A's
// (row=colid, k-chunk=quad), and A,B are rows of the same matrix.
__global__ __launch_bounds__(256) void norm_cast_k(
    const float* __restrict__ f1, const float* __restrict__ f2,
    unsigned char* __restrict__ Fa, float* __restrict__ rowsum,
    float* __restrict__ out) {
  int wave = threadIdx.x >> 6;
  int lane = threadIdx.x & 63;
  int row = blockIdx.x * 4 + wave;
  const float* src = (row < HALF_N) ? (f1 + (size_t)row * DIM)
                                    : (f2 + (size_t)(row - HALF_N) * DIM);
  const float4* p = reinterpret_cast<const float4*>(src + lane * 8);
  float4 v0 = p[0];
  float4 v1 = p[1];
  float ss = v0.x*v0.x + v0.y*v0.y + v0.z*v0.z + v0.w*v0.w
           + v1.x*v1.x + v1.y*v1.y + v1.z*v1.z + v1.w*v1.w;
  #pragma unroll
  for (int off = 1; off < 64; off <<= 1) ss += __shfl_xor(ss, off);
  float scale = 1.0f / fmaxf(sqrtf(ss), 1e-12f);
  int lo = __builtin_amdgcn_cvt_pk_fp8_f32(v0.x * scale, v0.y * scale, 0, false);
  lo = __builtin_amdgcn_cvt_pk_fp8_f32(v0.z * scale, v0.w * scale, lo, true);
  int hi = __builtin_amdgcn_cvt_pk_fp8_f32(v1.x * scale, v1.y * scale, 0, false);
  hi = __builtin_amdgcn_cvt_pk_fp8_f32(v1.z * scale, v1.w * scale, hi, true);
  int2 val = make_int2(lo, hi);   // 8 fp8 bytes = k-unit u of group g
  int u = lane & 7;                     // k-unit within 64B group
  int g = lane >> 3;                    // k-group (0..7)
  int chunk = g * 4 + (u & 3);          // global 16B chunk index (0..31)
  int slot = u >> 2;                    // which 8B half of the chunk
  *reinterpret_cast<int2*>(Fa + (size_t)(row >> 4) * 8192 + chunk * 256 +
                           (row & 15) * 16 + slot * 8) = val;
  if (lane == 0) rowsum[row] = 0.0f;
  if (blockIdx.x == 0 && threadIdx.x == 0) out[0] = 0.0f;
}

// Kernel 2: symmetric upper-triangle sim GEMM (fp8 e4m3 16x16x32, non-scaled;
// the MX-scaled builtin spills v8i32 via scratch on this ROCm — R1-R3. Do not
// retry.)
//
// R7 structure: ZERO-SYNC K-loop. Every LDS-staged variant (R0/R4/R6: LDS B
// + barriers, with/without dbuf/counted-vmcnt) landed at 42-55 µs with
// MfmaUtil <=29% and ~43% dual-idle — the barrier lockstep itself was the
// bottleneck at this short K (8 rounds). Here BOTH operands are loaded
// per-wave straight from the L2-resident fragment-major Fa (each 256B
// segment shared by exactly 2 waves -> partial L1 reuse; total L2 traffic
// 2080 x 256 KB = 532 MB @ 34.5 TB/s ~ 15 us, overlapping the 17.5 us MFMA
// floor). No LDS for operands, NO barriers in the K-loop: waves free-run and
// the MFMA pipe is fed by whichever of ~12 waves/CU is ready. 1-round
// register prefetch; acc 64 + frag 64 + ptr/misc ~ 155 regs under the
// (256,3) cap of 170 -> 3 blocks/CU.
__global__ __launch_bounds__(256, 3) void sym_gemm_k(
    const unsigned char* __restrict__ Fa,
    float* __restrict__ rowsum, float* __restrict__ pairsim) {
  // XCD-contiguous remap: each XCD (bx%8) gets a contiguous 260-block range
  int bx = blockIdx.x;
  int gbx = (bx & 7) * (NBLOCKS / 8) + (bx >> 3);
  int rb = 0, rem = gbx;
  while (rem >= NRB - rb) { rem -= NRB - rb; ++rb; }
  const int cb = rb + rem;
  const int row0 = rb * 128, col0 = cb * 128;

  const int tid = threadIdx.x;
  const int wave = tid >> 6;
  const int lane = tid & 63;
  const int quad = lane >> 4;
  const int colid = lane & 15;
  const int wr0 = (wave >> 1) * 64;   // wave's row offset within tile
  const int wc0 = (wave & 1) * 64;    // wave's col offset within tile

  __shared__ float redrow[128];
  __shared__ float redcol[128];
  if (tid < 128) redrow[tid] = 0.0f;
  else           redcol[tid - 128] = 0.0f;

  // Fragment pointers: panel (r>>4)*8192 + chunk(kc*4+quad)*256 + colid*16.
  // Quarter-wave (fixed quad, colid 0..15) reads 256 B contiguous.
  const unsigned char* agp[4];
  const unsigned char* bgp[4];
  #pragma unroll
  for (int t = 0; t < 4; ++t) {
    agp[t] = Fa + (size_t)((row0 + wr0 + t * 16) >> 4) * 8192 +
             quad * 256 + colid * 16;
    bgp[t] = Fa + (size_t)((col0 + wc0 + t * 16) >> 4) * 8192 +
             quad * 256 + colid * 16;
  }

  f32x4 acc[4][4];
  #pragma unroll
  for (int t = 0; t < 4; ++t)
    #pragma unroll
    for (int u = 0; u < 4; ++u) acc[t][u] = (f32x4){0.f, 0.f, 0.f, 0.f};

  // Prologue: round-0 fragments.
  long2v af[4], bf[4];
  #pragma unroll
  for (int t = 0; t < 4; ++t)
    af[t] = *reinterpret_cast<const long2v*>(agp[t]);
  #pragma unroll
  for (int u = 0; u < 4; ++u)
    bf[u] = *reinterpret_cast<const long2v*>(bgp[u]);

  #pragma unroll
  for (int kc = 0; kc < 8; ++kc) {
    // Prefetch next round while this round's 32 MFMAs run (no barriers:
    // the only consumer of these loads is next iteration's MFMA block).
    long2v afn[4], bfn[4];
    if (kc < 7) {
      #pragma unroll
      for (int t = 0; t < 4; ++t)
        afn[t] = *reinterpret_cast<const long2v*>(agp[t] + (kc + 1) * 1024);
      #pragma unroll
      for (int u = 0; u < 4; ++u)
        bfn[u] = *reinterpret_cast<const long2v*>(bgp[u] + (kc + 1) * 1024);
    }
    #pragma unroll
    for (int s = 0; s < 2; ++s)
      #pragma unroll
      for (int t = 0; t < 4; ++t)
        #pragma unroll
        for (int u = 0; u < 4; ++u)
          acc[t][u] = __builtin_amdgcn_mfma_f32_16x16x32_fp8_fp8(
              af[t][s], bf[u][s], acc[t][u], 0, 0, 0);
    if (kc < 7) {
      #pragma unroll
      for (int t = 0; t < 4; ++t) af[t] = afn[t];
      #pragma unroll
      for (int u = 0; u < 4; ++u) bf[u] = bfn[u];
    }
  }

  // One barrier in the whole kernel: makes the redrow/redcol zero-init
  // visible before any wave's atomic accumulation (the K-loop no longer
  // contains the barriers that used to provide this).
  __syncthreads();

  // Epilogue. C/D layout: col = lane&15, row = quad*4 + reg (m89-verified,
  // dtype-independent on gfx950).
  float re[4][4];
  float ce[4];
  #pragma unroll
  for (int t = 0; t < 4; ++t)
    #pragma unroll
    for (int r = 0; r < 4; ++r) re[t][r] = 0.0f;
  #pragma unroll
  for (int u = 0; u < 4; ++u) ce[u] = 0.0f;

  #pragma unroll
  for (int t = 0; t < 4; ++t) {
    #pragma unroll
    for (int u = 0; u < 4; ++u) {
      f32x4 a = acc[t][u];
      const int gc = col0 + wc0 + u * 16 + colid;
      #pragma unroll
      for (int r = 0; r < 4; ++r) {
        int grow = row0 + wr0 + t * 16 + quad * 4 + r;
        float sim = a[r] * INV_T;
        float e = (gc > grow) ? __expf(sim) : 0.0f;  // strict upper triangle
        re[t][r] += e;
        ce[u] += e;
        if (gc == grow + HALF_N && grow < HALF_N) {
          pairsim[grow] = sim;         // unique writer per pair
          pairsim[gc] = sim;
        }
      }
    }
  }

  // Row sums: reduce across the 16 col-lanes, LDS-accumulate.
  #pragma unroll
  for (int t = 0; t < 4; ++t)
    #pragma unroll
    for (int r = 0; r < 4; ++r) {
      float v = re[t][r];
      v += __shfl_xor(v, 1); v += __shfl_xor(v, 2);
      v += __shfl_xor(v, 4); v += __shfl_xor(v, 8);
      if (colid == 0) atomicAdd(&redrow[wr0 + t * 16 + quad * 4 + r], v);
    }
  // Col sums: reduce across the 4 quads (this wave's 64 rows).
  #pragma unroll
  for (int u = 0; u < 4; ++u) {
    float v = ce[u];
    v += __shfl_xor(v, 16); v += __shfl_xor(v, 32);
    if (lane < 16) atomicAdd(&redcol[wc0 + u * 16 + colid], v);
  }
  __syncthreads();
  if (tid < 128) atomicAdd(&rowsum[row0 + tid], redrow[tid]);
  else           atomicAdd(&rowsum[col0 + tid - 128], redcol[tid - 128]);
}

// Kernel 3: loss partials. 32 blocks x 256 threads, one row each;
// per-wave reduce then one atomicAdd per wave into out (zeroed in kernel 1).
__global__ __launch_bounds__(256) void finalize_k(
    const float* __restrict__ rowsum, const float* __restrict__ pairsim,
    float* __restrict__ out) {
  int i = blockIdx.x * 256 + threadIdx.x;
  float local = logf(rowsum[i]) - pairsim[i];
  #pragma unroll
  for (int off = 1; off < 64; off <<= 1) local += __shfl_xor(local, off);
  if ((threadIdx.x & 63) == 0)
    atomicAdd(out, local * (1.0f / (float)NROWS));
}

extern "C" void kernel_launch(void* const* d_in, const int* in_sizes, int n_in,
                              void* d_out, int out_size, void* d_ws, size_t ws_size,
                              hipStream_t stream) {
  const float* f1 = (const float*)d_in[0];
  const float* f2 = (const float*)d_in[1];
  unsigned char* Fa = (unsigned char*)d_ws;                     // 4 MB fp8
  float* rowsum = (float*)(Fa + (size_t)NROWS * DIM);
  float* pairsim = rowsum + NROWS;
  float* out = (float*)d_out;

  norm_cast_k<<<NROWS / 4, 256, 0, stream>>>(f1, f2, Fa, rowsum, out);
  sym_gemm_k<<<NBLOCKS, 256, 0, stream>>>(Fa, rowsum, pairsim);
  finalize_k<<<NROWS / 256, 256, 0, stream>>>(rowsum, pairsim, out);
}